// Round 1
// baseline (679.092 us; speedup 1.0000x reference)
//
#include <hip/hip_runtime.h>
#include <math.h>

#define HEADS 16
#define HDIM 1024
#define NB 16
#define SEQ 4096
#define SCH 128
#define NCH (SEQ / SCH) /* 32 */
#define INV_SQRT 0.03125f /* 1/sqrt(1024) */

// Reduce 16 per-lane values across 64 lanes.
// Returns the full sum of p[h] over all lanes, where h = (lane>>1)&15.
// Lanes {0,2,...,30} hold h = lane>>1 canonically.
__device__ __forceinline__ float reduce16_to_lane(const float p[16], int lane) {
  float r8[8];
#pragma unroll
  for (int i = 0; i < 8; ++i) {
    float send = (lane & 16) ? p[i] : p[i + 8];
    float recv = __shfl_xor(send, 16, 64);
    r8[i] = ((lane & 16) ? p[i + 8] : p[i]) + recv;
  }
  float r4[4];
#pragma unroll
  for (int i = 0; i < 4; ++i) {
    float send = (lane & 8) ? r8[i] : r8[i + 4];
    float recv = __shfl_xor(send, 8, 64);
    r4[i] = ((lane & 8) ? r8[i + 4] : r8[i]) + recv;
  }
  float r2[2];
#pragma unroll
  for (int i = 0; i < 2; ++i) {
    float send = (lane & 4) ? r2[0] * 0.f + ((lane & 4) ? r4[i] : r4[i + 2]) : r4[i + 2];
    // (written plainly below to avoid confusion)
    send = (lane & 4) ? r4[i] : r4[i + 2];
    float recv = __shfl_xor(send, 4, 64);
    r2[i] = ((lane & 4) ? r4[i + 2] : r4[i]) + recv;
  }
  float send = (lane & 2) ? r2[0] : r2[1];
  float recv = __shfl_xor(send, 2, 64);
  float x = ((lane & 2) ? r2[1] : r2[0]) + recv;
  x += __shfl_xor(x, 1, 64);
  x += __shfl_xor(x, 32, 64);
  return x;
}

// K1: q[b,i] = query[b,:]·Wq[i,:] + bq[i]   (B x 1024, 16M MAC)
__global__ __launch_bounds__(256) void k1_qproj(
    const float* __restrict__ query, const float* __restrict__ Wq,
    const float* __restrict__ bq, float* __restrict__ qout) {
  __shared__ __align__(16) float qlds[NB * HDIM]; // 64KB: whole query
  int t = threadIdx.x;
#pragma unroll
  for (int p = 0; p < 16; ++p)
    ((float4*)qlds)[t + p * 256] = ((const float4*)query)[t + p * 256];
  __syncthreads();
  int lane = t & 63, wave = t >> 6;
  int i = blockIdx.x * 4 + wave; // grid 256 -> i in [0,1024)
  float p_[NB];
#pragma unroll
  for (int b = 0; b < NB; ++b) p_[b] = 0.f;
#pragma unroll
  for (int it = 0; it < 4; ++it) {
    int j = it * 256 + lane * 4;
    float4 w4 = *(const float4*)(Wq + (size_t)i * HDIM + j);
#pragma unroll
    for (int b = 0; b < NB; ++b) {
      float4 q4 = *(const float4*)(qlds + b * HDIM + j);
      p_[b] += w4.x * q4.x + w4.y * q4.y + w4.z * q4.z + w4.w * q4.w;
    }
  }
  float x = reduce16_to_lane(p_, lane);
  if (lane < 32 && !(lane & 1)) {
    int b = lane >> 1;
    qout[b * HDIM + i] = x + bq[i];
  }
}

// K2: wqk[b,h,j] = (1/32) * sum_d q[b,h*64+d] * Wk[h*64+d, j]
//     qbk[b,h]   = (1/32) * sum_d q[b,h*64+d] * bk[h*64+d]
__global__ __launch_bounds__(256) void k2_wproj(
    const float* __restrict__ q, const float* __restrict__ Wk,
    const float* __restrict__ bk, float* __restrict__ wqk,
    float* __restrict__ qbk) {
  int t = threadIdx.x;
  int h = blockIdx.x;
  if (h < HEADS) {
    __shared__ __align__(16) float qlds[NB * 64];
    {
      int b = t >> 4, d4 = (t & 15) * 4;
      *(float4*)(qlds + b * 64 + d4) =
          *(const float4*)(q + (size_t)b * HDIM + h * 64 + d4);
    }
    __syncthreads();
    float4 acc[NB];
#pragma unroll
    for (int b = 0; b < NB; ++b) acc[b] = make_float4(0.f, 0.f, 0.f, 0.f);
    for (int d = 0; d < 64; ++d) {
      float4 w4 = *(const float4*)(Wk + (size_t)(h * 64 + d) * HDIM + t * 4);
#pragma unroll
      for (int b = 0; b < NB; ++b) {
        float qv = qlds[b * 64 + d];
        acc[b].x += qv * w4.x;
        acc[b].y += qv * w4.y;
        acc[b].z += qv * w4.z;
        acc[b].w += qv * w4.w;
      }
    }
#pragma unroll
    for (int b = 0; b < NB; ++b) {
      float4 o = make_float4(acc[b].x * INV_SQRT, acc[b].y * INV_SQRT,
                             acc[b].z * INV_SQRT, acc[b].w * INV_SQRT);
      *(float4*)(wqk + (size_t)(b * HEADS + h) * HDIM + t * 4) = o;
    }
  } else {
    // one extra block computes qbk for all (b,h)
    int b = t >> 4, hh = t & 15;
    float s = 0.f;
    for (int d = 0; d < 64; ++d)
      s += q[(size_t)b * HDIM + hh * 64 + d] * bk[hh * 64 + d];
    qbk[b * HEADS + hh] = s * INV_SQRT;
  }
}

// K3 (dominant): single fused streaming pass over key_ and value.
// Per (b, s-chunk) block: scores (16 heads) -> softmax over heads ->
// accumulate A[h][j] += att[h]*value[j] and l[h] += att[h] in registers.
__global__ __launch_bounds__(256, 2) void k3_attn(
    const float* __restrict__ key, const float* __restrict__ value,
    const float* __restrict__ wqk, const float* __restrict__ qbk,
    float* __restrict__ A_part, float* __restrict__ l_part) {
  int t = threadIdx.x;
  int lane = t & 63, wave = t >> 6;
  int b = blockIdx.x / NCH;
  int c = blockIdx.x % NCH;
  __shared__ __align__(16) float sp[2][4][16]; // double-buffered wave partials

  float4 wq[HEADS]; // this thread's j-slice of wqk for all heads (pre-scaled)
#pragma unroll
  for (int h = 0; h < HEADS; ++h)
    wq[h] = *(const float4*)(wqk + (size_t)(b * HEADS + h) * HDIM + t * 4);
  float4 qb4[4];
#pragma unroll
  for (int hq = 0; hq < 4; ++hq)
    qb4[hq] = *(const float4*)(qbk + b * HEADS + hq * 4);

  float4 Aacc[HEADS];
#pragma unroll
  for (int h = 0; h < HEADS; ++h) Aacc[h] = make_float4(0.f, 0.f, 0.f, 0.f);
  float lacc[HEADS];
#pragma unroll
  for (int h = 0; h < HEADS; ++h) lacc[h] = 0.f;

  const float4* kptr =
      (const float4*)(key + ((size_t)b * SEQ + (size_t)c * SCH) * HDIM) + t;
  const float4* vptr =
      (const float4*)(value + ((size_t)b * SEQ + (size_t)c * SCH) * HDIM) + t;

  // distance-2 prefetch to cover ~900cy HBM latency
  float4 kf0 = kptr[0], vf0 = vptr[0];
  float4 kf1 = kptr[256], vf1 = vptr[256];

  for (int s = 0; s < SCH; ++s) {
    float4 kc = kf0, vc = vf0;
    kf0 = kf1;
    vf0 = vf1;
    if (s + 2 < SCH) {
      kf1 = kptr[(size_t)(s + 2) * 256];
      vf1 = vptr[(size_t)(s + 2) * 256];
    }
    // per-head partial dot over this thread's 4 j's
    float p_[16];
#pragma unroll
    for (int h = 0; h < HEADS; ++h)
      p_[h] = kc.x * wq[h].x + kc.y * wq[h].y + kc.z * wq[h].z + kc.w * wq[h].w;
    float x = reduce16_to_lane(p_, lane);
    int buf = s & 1;
    if (lane < 32 && !(lane & 1)) sp[buf][wave][lane >> 1] = x;
    __syncthreads();
    // final scores = sum over 4 waves + qbk (already includes 1/32 scale)
    float sc[16];
#pragma unroll
    for (int hq = 0; hq < 4; ++hq) {
      float4 a0 = *(const float4*)&sp[buf][0][hq * 4];
      float4 a1 = *(const float4*)&sp[buf][1][hq * 4];
      float4 a2 = *(const float4*)&sp[buf][2][hq * 4];
      float4 a3 = *(const float4*)&sp[buf][3][hq * 4];
      sc[hq * 4 + 0] = a0.x + a1.x + a2.x + a3.x + qb4[hq].x;
      sc[hq * 4 + 1] = a0.y + a1.y + a2.y + a3.y + qb4[hq].y;
      sc[hq * 4 + 2] = a0.z + a1.z + a2.z + a3.z + qb4[hq].z;
      sc[hq * 4 + 3] = a0.w + a1.w + a2.w + a3.w + qb4[hq].w;
    }
    // softmax over 16 heads (scores bounded ~|3|: skip max-subtraction)
    float e[16];
#pragma unroll
    for (int h = 0; h < HEADS; ++h) e[h] = __expf(sc[h]);
    float s01 = e[0] + e[1], s23 = e[2] + e[3], s45 = e[4] + e[5],
          s67 = e[6] + e[7], s89 = e[8] + e[9], sab = e[10] + e[11],
          scd = e[12] + e[13], sef = e[14] + e[15];
    float sum = ((s01 + s23) + (s45 + s67)) + ((s89 + sab) + (scd + sef));
    float rinv = 1.0f / sum;
#pragma unroll
    for (int h = 0; h < HEADS; ++h) {
      float a = e[h] * rinv;
      lacc[h] += a;
      Aacc[h].x += a * vc.x;
      Aacc[h].y += a * vc.y;
      Aacc[h].z += a * vc.z;
      Aacc[h].w += a * vc.w;
    }
  }
  size_t base = (size_t)(b * NCH + c) * HEADS * HDIM;
#pragma unroll
  for (int h = 0; h < HEADS; ++h)
    *(float4*)(A_part + base + (size_t)h * HDIM + t * 4) = Aacc[h];
  if (t == 0) {
#pragma unroll
    for (int h = 0; h < HEADS; ++h)
      l_part[(b * NCH + c) * HEADS + h] = lacc[h];
  }
}

// K4: A[b,h,:] = sum_c A_part; o1[b,h*64+d] = A·Wv[h*64+d,:] + l*bv
__global__ __launch_bounds__(256) void k4_vproj(
    const float* __restrict__ A_part, const float* __restrict__ l_part,
    const float* __restrict__ Wv, const float* __restrict__ bv,
    float* __restrict__ o1) {
  __shared__ __align__(16) float Alds[HDIM];
  __shared__ float llds;
  int t = threadIdx.x;
  int b = blockIdx.x >> 4, h = blockIdx.x & 15;
  float4 a = make_float4(0.f, 0.f, 0.f, 0.f);
  for (int cc = 0; cc < NCH; ++cc) {
    float4 v = *(const float4*)(A_part +
                                ((size_t)(b * NCH + cc) * HEADS + h) * HDIM +
                                t * 4);
    a.x += v.x;
    a.y += v.y;
    a.z += v.z;
    a.w += v.w;
  }
  *(float4*)(Alds + t * 4) = a;
  if (t < 32) {
    float lv = l_part[(b * NCH + t) * HEADS + h];
    lv += __shfl_xor(lv, 1, 64);
    lv += __shfl_xor(lv, 2, 64);
    lv += __shfl_xor(lv, 4, 64);
    lv += __shfl_xor(lv, 8, 64);
    lv += __shfl_xor(lv, 16, 64);
    if (t == 0) llds = lv;
  }
  __syncthreads();
  int lane = t & 63, wave = t >> 6;
  float lval = llds;
#pragma unroll
  for (int p = 0; p < 16; ++p) {
    int d = p * 4 + wave;
    float acc = 0.f;
#pragma unroll
    for (int it = 0; it < 4; ++it) {
      int j = it * 256 + lane * 4;
      float4 w4 = *(const float4*)(Wv + (size_t)(h * 64 + d) * HDIM + j);
      float4 a4 = *(const float4*)(Alds + j);
      acc += w4.x * a4.x + w4.y * a4.y + w4.z * a4.z + w4.w * a4.w;
    }
    acc += __shfl_xor(acc, 1, 64);
    acc += __shfl_xor(acc, 2, 64);
    acc += __shfl_xor(acc, 4, 64);
    acc += __shfl_xor(acc, 8, 64);
    acc += __shfl_xor(acc, 16, 64);
    acc += __shfl_xor(acc, 32, 64);
    if (lane == 0)
      o1[(size_t)b * HDIM + h * 64 + d] = acc + lval * bv[h * 64 + d];
  }
}

// K5: out[b,i] = o1[b,:]·Wf[i,:] + bf[i]
__global__ __launch_bounds__(256) void k5_final(
    const float* __restrict__ o1, const float* __restrict__ Wf,
    const float* __restrict__ bf, float* __restrict__ out) {
  __shared__ __align__(16) float olds[NB * HDIM]; // 64KB: whole o1
  int t = threadIdx.x;
#pragma unroll
  for (int p = 0; p < 16; ++p)
    ((float4*)olds)[t + p * 256] = ((const float4*)o1)[t + p * 256];
  __syncthreads();
  int lane = t & 63, wave = t >> 6;
  int i = blockIdx.x * 4 + wave; // grid 256 -> i in [0,1024)
  float p_[NB];
#pragma unroll
  for (int b = 0; b < NB; ++b) p_[b] = 0.f;
#pragma unroll
  for (int it = 0; it < 4; ++it) {
    int j = it * 256 + lane * 4;
    float4 w4 = *(const float4*)(Wf + (size_t)i * HDIM + j);
#pragma unroll
    for (int b = 0; b < NB; ++b) {
      float4 q4 = *(const float4*)(olds + b * HDIM + j);
      p_[b] += w4.x * q4.x + w4.y * q4.y + w4.z * q4.z + w4.w * q4.w;
    }
  }
  float x = reduce16_to_lane(p_, lane);
  if (lane < 32 && !(lane & 1)) {
    int bb = lane >> 1;
    out[(size_t)bb * HDIM + i] = x + bf[i];
  }
}

extern "C" void kernel_launch(void* const* d_in, const int* in_sizes, int n_in,
                              void* d_out, int out_size, void* d_ws,
                              size_t ws_size, hipStream_t stream) {
  const float* query = (const float*)d_in[0];
  const float* key_ = (const float*)d_in[1];
  const float* value = (const float*)d_in[2];
  const float* Wq = (const float*)d_in[3];
  const float* bq = (const float*)d_in[4];
  const float* Wk = (const float*)d_in[5];
  const float* bk = (const float*)d_in[6];
  const float* Wv = (const float*)d_in[7];
  const float* bv = (const float*)d_in[8];
  const float* Wf = (const float*)d_in[9];
  const float* bf = (const float*)d_in[10];
  float* out = (float*)d_out;

  // workspace layout (floats); total ~8.7M floats = ~35 MB
  float* ws = (float*)d_ws;
  float* wqk = ws;                  // 16*16*1024   = 262144
  float* qbk = ws + 262144;         // 16*16        = 256
  float* qbuf = ws + 262400;        // 16*1024      = 16384
  float* o1 = ws + 278784;          // 16*1024      = 16384
  float* l_part = ws + 295168;      // 16*32*16     = 8192
  float* A_part = ws + 303360;      // 16*32*16*1024 = 8388608

  k1_qproj<<<256, 256, 0, stream>>>(query, Wq, bq, qbuf);
  k2_wproj<<<HEADS + 1, 256, 0, stream>>>(qbuf, Wk, bk, wqk, qbk);
  k3_attn<<<NB * NCH, 256, 0, stream>>>(key_, value, wqk, qbk, A_part, l_part);
  k4_vproj<<<NB * HEADS, 256, 0, stream>>>(A_part, l_part, Wv, bv, o1);
  k5_final<<<256, 256, 0, stream>>>(o1, Wf, bf, out);
}